// Round 7
// baseline (239.974 us; speedup 1.0000x reference)
//
#include <hip/hip_runtime.h>
#include <stdint.h>

// Izhikevich spiking neuron scan — screen-and-fill.
// x: [T=512, N=65536] f32. out: [T, N] f32 spike train (0.0/1.0).
//
// R7 algorithmic move: firing (v >= 0.3) requires 4v^2+5v+1.4-r+x >= 153.6.
// Pre-fire |v| <= (1.4+max|x|)/512: for max|x| <= 140, v <= 143.3/512 = 0.28
// < 0.3 (fixed-point bound, 7% margin, holds under fp32 rounding). So if
// ALL |x| < 140, the output is identically zero — for N(0,1) inputs
// (max ~5.5) this always holds. Split into:
//   K1: pure linear read of x + |x|>=140 block-OR -> flags in ws
//       (no recurrence feeding loads — the pattern that measures 6.3 TB/s).
//   K2: read flags (8 KiB, uniform branch): clear -> linear zero-fill of out
//       (the 6.7 TB/s fill pattern); set -> full-T serial fallback (exact
//       for any input; never taken for this distribution).
// R1-R6 showed any kernel whose loads feed the serial recurrence caps at
// ~2.5 TB/s regardless of structure (ILP/occupancy/vectorization/ring all
// neutral); this removes the recurrence from the hot path entirely while
// remaining correct for all inputs via the fallback.

#define T_STEPS   512
#define N_NEUR    65536
#define DT        (1.0f / 512.0f)
#define TOTAL_F4  ((size_t)T_STEPS * N_NEUR / 4)   // 8M float4 = 128 MiB
#define SCR_BLK   2048
#define PER_THR   (TOTAL_F4 / (SCR_BLK * 256))     // 16 float4 per thread
#define XMAX      140.0f

// ---- K1: screen. Pure linear grid-stride read, block-OR of |x|>=XMAX. ----
__global__ __launch_bounds__(256) void izi_screen(const float4* __restrict__ x,
                                                  unsigned* __restrict__ flags) {
    const size_t g = (size_t)blockIdx.x * 256 + threadIdx.x;
    bool hot = false;
    #pragma unroll
    for (int i = 0; i < (int)PER_THR; ++i) {
        const float4 a = x[(size_t)i * (SCR_BLK * 256) + g];
        hot |= (fabsf(a.x) >= XMAX) | (fabsf(a.y) >= XMAX) |
               (fabsf(a.z) >= XMAX) | (fabsf(a.w) >= XMAX);
    }
    const unsigned long long b = __ballot(hot);
    __shared__ unsigned wany[4];
    if ((threadIdx.x & 63) == 0) wany[threadIdx.x >> 6] = (b != 0ull) ? 1u : 0u;
    __syncthreads();
    if (threadIdx.x == 0)
        flags[blockIdx.x] = wany[0] | wany[1] | wany[2] | wany[3];
}

__device__ __forceinline__ float izi_step(float xt, float& v, float& r) {
    v = (4.0f * v * v + 5.0f * v + 1.4f - r + xt) * DT;
    r = v * (0.02f * (0.2f - 1.0f) * DT);
    const bool fire = v >= 0.3f;
    if (fire) { v = -0.065f; r += 0.008f; }
    return fire ? 1.0f : 0.0f;
}

// ---- K2: flags clear -> linear zero-fill; else exact full-T fallback. ----
__global__ __launch_bounds__(256) void izi_fill_or_scan(const float* __restrict__ x,
                                                        const unsigned* __restrict__ flags,
                                                        float4* __restrict__ out4) {
    __shared__ unsigned s_any;
    if (threadIdx.x == 0) s_any = 0u;
    __syncthreads();
    {   // 2048 flags = 512 uint4; 256 threads read 2 each
        const uint4* f4 = (const uint4*)flags;
        const uint4 a = f4[threadIdx.x];
        const uint4 b = f4[threadIdx.x + 256];
        const unsigned m = a.x | a.y | a.z | a.w | b.x | b.y | b.z | b.w;
        if (m) atomicOr(&s_any, 1u);   // LDS atomic; never taken when all-cold
    }
    __syncthreads();

    if (s_any == 0u) {
        // Fast path: pure linear float4 zero-fill (fill-kernel pattern).
        const size_t g = (size_t)blockIdx.x * 256 + threadIdx.x;
        const float4 z = make_float4(0.0f, 0.0f, 0.0f, 0.0f);
        #pragma unroll
        for (int i = 0; i < (int)PER_THR; ++i)
            out4[(size_t)i * (SCR_BLK * 256) + g] = z;
    } else {
        // Exact fallback: full serial scan, one thread per neuron (blocks 0..255).
        if (blockIdx.x < N_NEUR / 256) {
            const int n = blockIdx.x * 256 + threadIdx.x;
            float* out = (float*)out4;
            float v = -0.065f, r = 0.0f;
            for (int t = 0; t < T_STEPS; ++t) {
                const float xt = x[(size_t)t * N_NEUR + n];
                out[(size_t)t * N_NEUR + n] = izi_step(xt, v, r);
            }
        }
    }
}

// ---- Honest fused fallback if ws can't hold the flags (never expected). ----
__global__ __launch_bounds__(256) void izi_fused(const float* __restrict__ x,
                                                 float* __restrict__ out) {
    const int n = blockIdx.x * 256 + threadIdx.x;
    float v = -0.065f, r = 0.0f;
    #pragma unroll 8
    for (int t = 0; t < T_STEPS; ++t) {
        const float xt = x[(size_t)t * N_NEUR + n];
        out[(size_t)t * N_NEUR + n] = izi_step(xt, v, r);
    }
}

extern "C" void kernel_launch(void* const* d_in, const int* in_sizes, int n_in,
                              void* d_out, int out_size, void* d_ws, size_t ws_size,
                              hipStream_t stream) {
    const float* x = (const float*)d_in[0];
    if (ws_size >= SCR_BLK * sizeof(unsigned)) {
        unsigned* flags = (unsigned*)d_ws;
        izi_screen<<<dim3(SCR_BLK), dim3(256), 0, stream>>>((const float4*)x, flags);
        izi_fill_or_scan<<<dim3(SCR_BLK), dim3(256), 0, stream>>>(x, flags,
                                                                  (float4*)d_out);
    } else {
        izi_fused<<<dim3(N_NEUR / 256), dim3(256), 0, stream>>>(x, (float*)d_out);
    }
}